// Round 16
// baseline (190.601 us; speedup 1.0000x reference)
//
#include <hip/hip_runtime.h>
#include <hip/hip_bf16.h>
#include <stdint.h>

// Problem constants
#define L_DIM 1024
#define C_DIM 512       // channels (elements)
#define CB4 256         // fp4 row stride in BYTES (512 elems * 4 bit)
#define N_BATCH 32
#define M_NEG 4096
#define NROWS (N_BATCH * L_DIM) // 32768

typedef float f32x4 __attribute__((ext_vector_type(4)));
typedef int i32x4 __attribute__((ext_vector_type(4)));
typedef int i32x8 __attribute__((ext_vector_type(8)));

// E stored as fp4 e2m1 scaled by 32 (clip at |x|=0.1875 ~ 4.3 sigma);
// e8m0 scale 122 (=2^-5) on both MFMA operands gives exact 1/1024 comp.
#define E4_SCALE 32.0f
#define MX_SCALE 122
#define FMT_FP4 4

// DMA immediate offset must be a compile-time constant -> template param.
template <int GOFF>
__device__ __forceinline__ void gl_lds16(const uint8_t* g, uint8_t* l) {
  __builtin_amdgcn_global_load_lds(
      (const __attribute__((address_space(1))) void*)g,
      (__attribute__((address_space(3))) void*)l, 16, GOFF, 0);
}

// fp4 e2m1 round-to-nearest encode of pre-scaled value.
__device__ __forceinline__ uint32_t fp4_enc(float x) {
  const uint32_t s = (__float_as_uint(x) >> 31) << 3;
  const float a = fabsf(x);
  uint32_t c;
  c = a < 0.25f ? 0u
    : a < 0.75f ? 1u
    : a < 1.25f ? 2u
    : a < 1.75f ? 3u
    : a < 2.5f  ? 4u
    : a < 3.5f  ? 5u
    : a < 5.0f  ? 6u : 7u;
  return s | c;
}

// fp4 operand tuple: HW reads only v[0:3] for FMT_FP4; upper half undef.
__device__ __forceinline__ i32x8 fp4_op(i32x4 d) {
  return __builtin_shufflevector(d, d, 0, 1, 2, 3, -1, -1, -1, -1);
}

// LDS swizzle phase (verified 0-conflict in R14): bank window = 128 B =
// two 64 B rows -> phase advances per 2 rows.
__device__ __forceinline__ int swz(int row) { return (row >> 1) & 3; }

// ---------------------------------------------------------------------------
// Kernel 1: row-wise L2 normalize fp32 [32768, 512] -> fp4 e2m1 (x32 scaled).
// Blocks 0..1151 zero the 1 MB rowsum8 replicas + 128 KB simpos; block 0
// zeroes the loss scalar.
// ---------------------------------------------------------------------------
__global__ __launch_bounds__(256) void k_normalize(const float* __restrict__ emb,
                                                   uint8_t* __restrict__ out,
                                                   float* __restrict__ zerobuf,
                                                   float* __restrict__ loss_out) {
  if (blockIdx.x < 1152) zerobuf[blockIdx.x * 256 + threadIdx.x] = 0.0f;
  if (blockIdx.x == 0 && threadIdx.x == 0) loss_out[0] = 0.0f;
  const int lane = threadIdx.x & 63;
  const int wave = threadIdx.x >> 6;
  const long row = (long)blockIdx.x * 4 + wave;
  const float4* src = (const float4*)(emb + row * C_DIM);
  float4 v0 = src[2 * lane];
  float4 v1 = src[2 * lane + 1];
  float ss = v0.x * v0.x + v0.y * v0.y + v0.z * v0.z + v0.w * v0.w +
             v1.x * v1.x + v1.y * v1.y + v1.z * v1.z + v1.w * v1.w;
#pragma unroll
  for (int off = 1; off < 64; off <<= 1) ss += __shfl_xor(ss, off, 64);
  const float s = E4_SCALE / fmaxf(sqrtf(ss), 1e-12f);
  uint32_t pk = fp4_enc(v0.x * s)        | (fp4_enc(v0.y * s) << 4) |
                (fp4_enc(v0.z * s) << 8) | (fp4_enc(v0.w * s) << 12) |
                (fp4_enc(v1.x * s) << 16)| (fp4_enc(v1.y * s) << 20) |
                (fp4_enc(v1.z * s) << 24)| (fp4_enc(v1.w * s) << 28);
  ((uint32_t*)(out + row * CB4))[lane] = pk;
}

// ---------------------------------------------------------------------------
// Kernel 2 (FUSED), 3072 blocks:
// MODE 0 (bid < 1024): NEG-STATIONARY PERSISTENT TILES (R15 structure).
//   128 neg rows idx-gathered ONCE into 4 full-K LDS slabs (32 KB), then
//   8 E-tiles streamed through an 8 KB slab. Register-only rowsum reduce.
//   R16 FIX: atomics go to the block's own XCD-local rowsum REPLICA
//   (rowsum8[bid&7]) -- R15's single copy had 32 writers per address
//   scattered over 8 non-coherent L2s -> every atomic line migrated
//   through HBM (WRITE_SIZE 5->62 MB, the whole regression).
//   XCD map: xcd=bid&7, slot=bid>>3: negTile=slot&31, eGroup=xcd*4+(slot>>5).
// MODE 1 (bid >= 1024): R14 structure verbatim (Gram x W epilogue);
//   its simpos atomics are already XCD-local under this map.
// LDS 40960 B, 64 VGPR + 64 AGPR -> 4 blocks/CU (~40% occupancy).
// ---------------------------------------------------------------------------
__global__ __launch_bounds__(256, 4) void k_gemm_fused(
    const uint8_t* __restrict__ E4, const int* __restrict__ idx,
    const float* __restrict__ W, float* __restrict__ rowsum8,
    float* __restrict__ simpos) {
  __shared__ __align__(16) unsigned char smem_raw[40960];

  const int tid = threadIdx.x;
  const int lane = tid & 63;
  const int wave = tid >> 6;
  const int wm = wave >> 1, wn = wave & 1;
  const int q = lane >> 4, c16 = lane & 15;

  const int bid = blockIdx.x;

  if (bid < 1024) {
    // ================= MODE 0: neg-stationary =================
    uint8_t* sN = (uint8_t*)smem_raw;        // 4 slabs [128][64B] = 32 KB
    uint8_t* sE = sN + 32768;                // [128][64B] = 8 KB
    const int xcd = bid & 7, slot = bid >> 3;
    const long negBase = (long)(slot & 31) * 128;
    const long eBase0 = (long)(xcd * 4 + (slot >> 5)) * 1024;  // 8 tiles
    float* myrs = rowsum8 + (long)xcd * NROWS;  // XCD-local replica

    // Gather-stage the 128 neg rows, full K (8 DMAs/thread, once).
    const uint8_t* pN[2];
#pragma unroll
    for (int r = 0; r < 2; ++r) {
      const int c = r * 256 + tid;          // chunk 0..511 per slab
      const int rw = c >> 2, cb = c & 3;
      pN[r] = E4 + (long)idx[negBase + rw] * CB4 + (cb ^ swz(rw)) * 16;
    }
    gl_lds16<0>(pN[0], sN + tid * 16);
    gl_lds16<0>(pN[1], sN + (256 + tid) * 16);
    gl_lds16<64>(pN[0], sN + 8192 + tid * 16);
    gl_lds16<64>(pN[1], sN + 8192 + (256 + tid) * 16);
    gl_lds16<128>(pN[0], sN + 16384 + tid * 16);
    gl_lds16<128>(pN[1], sN + 16384 + (256 + tid) * 16);
    gl_lds16<192>(pN[0], sN + 24576 + tid * 16);
    gl_lds16<192>(pN[1], sN + 24576 + (256 + tid) * 16);

    // E staging pointers (advance 32768 B per tile).
    const uint8_t* pE[2];
#pragma unroll
    for (int r = 0; r < 2; ++r) {
      const int c = r * 256 + tid;
      const int rw = c >> 2, cb = c & 3;
      pE[r] = E4 + (eBase0 + rw) * CB4 + (cb ^ swz(rw)) * 16;
    }

    // Hoisted LDS fragment byte-offsets.
    int ldsN[4], ldsE[4];
#pragma unroll
    for (int j = 0; j < 4; ++j) {
      const int rowN = wm * 64 + j * 16 + c16;
      ldsN[j] = rowN * 64 + (q ^ swz(rowN)) * 16;
      const int rowE = wn * 64 + j * 16 + c16;
      ldsE[j] = rowE * 64 + (q ^ swz(rowE)) * 16;
    }

    for (int et = 0; et < 8; ++et) {
      f32x4 acc[4][4] = {};
      auto kstep = [&](int ks) {
        __syncthreads();
        i32x8 efr[4];
#pragma unroll
        for (int j = 0; j < 4; ++j)
          efr[j] = fp4_op(*(const i32x4*)(sE + ldsE[j]));
#pragma unroll
        for (int i = 0; i < 4; ++i) {
          i32x8 nf = fp4_op(*(const i32x4*)(sN + ks * 8192 + ldsN[i]));
#pragma unroll
          for (int j = 0; j < 4; ++j)
            acc[i][j] = __builtin_amdgcn_mfma_scale_f32_16x16x128_f8f6f4(
                nf, efr[j], acc[i][j], FMT_FP4, FMT_FP4,
                0, MX_SCALE, 0, MX_SCALE);
        }
        __syncthreads();
      };
      gl_lds16<0>(pE[0], sE + tid * 16);
      gl_lds16<0>(pE[1], sE + (256 + tid) * 16);
      kstep(0);
      gl_lds16<64>(pE[0], sE + tid * 16);
      gl_lds16<64>(pE[1], sE + (256 + tid) * 16);
      kstep(1);
      gl_lds16<128>(pE[0], sE + tid * 16);
      gl_lds16<128>(pE[1], sE + (256 + tid) * 16);
      kstep(2);
      gl_lds16<192>(pE[0], sE + tid * 16);
      gl_lds16<192>(pE[1], sE + (256 + tid) * 16);
      kstep(3);
      pE[0] += 32768;
      pE[1] += 32768;

      // Register-only epilogue: myrs[E-col] += sum over 128 neg rows of
      // exp(sim). In-thread sum over i,r; q-shuffles (16,32); q==0 lanes
      // atomically add into the XCD-LOCAL replica.
      const long eCol = eBase0 + (long)et * 128 + wn * 64 + c16;
#pragma unroll
      for (int j = 0; j < 4; ++j) {
        float s = 0.0f;
#pragma unroll
        for (int i = 0; i < 4; ++i)
#pragma unroll
          for (int r = 0; r < 4; ++r) s += __expf(acc[i][j][r]);
        s += __shfl_xor(s, 16, 64);
        s += __shfl_xor(s, 32, 64);
        if (q == 0) atomicAdd(&myrs[eCol + j * 16], s);
      }
    }
  } else {
    // ================= MODE 1: Gram x W (R14 verbatim) =================
    uint8_t* sA = (uint8_t*)smem_raw;        // [128][64B] = 8 KB
    uint8_t* sB = sA + 8192;                 // [128][64B] = 8 KB
    const int t = bid - 1024;
    const int xcd = t & 7, slot = t >> 3;
    const long n = xcd * 4 + (slot & 3);
    const int inner = slot >> 2;             // 0..63
    const long rowBase = (long)(inner & 7) * 128;
    const long colBase = (long)(inner >> 3) * 128;
    const long aBase = n * L_DIM + rowBase;

    const uint8_t* pA[2];
    const uint8_t* pB[2];
#pragma unroll
    for (int r = 0; r < 2; ++r) {
      const int c = r * 256 + tid;
      const int rw = c >> 2, cb = c & 3;
      pA[r] = E4 + (aBase + rw) * CB4 + (cb ^ swz(rw)) * 16;
      pB[r] = E4 + (n * L_DIM + colBase + rw) * CB4 + (cb ^ swz(rw)) * 16;
    }
    int ldsB[4], ldsA[4];
#pragma unroll
    for (int j = 0; j < 4; ++j) {
      const int rowB = wn * 64 + j * 16 + c16;
      ldsB[j] = rowB * 64 + (q ^ swz(rowB)) * 16;
      const int rowA = wm * 64 + j * 16 + c16;
      ldsA[j] = rowA * 64 + (q ^ swz(rowA)) * 16;
    }

    f32x4 acc[4][4] = {};
    auto kstep = [&]() {
      __syncthreads();
      i32x8 bfr[4];
#pragma unroll
      for (int j = 0; j < 4; ++j)
        bfr[j] = fp4_op(*(const i32x4*)(sB + ldsB[j]));
#pragma unroll
      for (int i = 0; i < 4; ++i) {
        i32x8 af = fp4_op(*(const i32x4*)(sA + ldsA[i]));
#pragma unroll
        for (int j = 0; j < 4; ++j)
          acc[i][j] = __builtin_amdgcn_mfma_scale_f32_16x16x128_f8f6f4(
              af, bfr[j], acc[i][j], FMT_FP4, FMT_FP4,
              0, MX_SCALE, 0, MX_SCALE);
      }
      __syncthreads();
    };
    gl_lds16<0>(pA[0], sA + tid * 16);
    gl_lds16<0>(pA[1], sA + (256 + tid) * 16);
    gl_lds16<0>(pB[0], sB + tid * 16);
    gl_lds16<0>(pB[1], sB + (256 + tid) * 16);
    kstep();
    gl_lds16<64>(pA[0], sA + tid * 16);
    gl_lds16<64>(pA[1], sA + (256 + tid) * 16);
    gl_lds16<64>(pB[0], sB + tid * 16);
    gl_lds16<64>(pB[1], sB + (256 + tid) * 16);
    kstep();
    gl_lds16<128>(pA[0], sA + tid * 16);
    gl_lds16<128>(pA[1], sA + (256 + tid) * 16);
    gl_lds16<128>(pB[0], sB + tid * 16);
    gl_lds16<128>(pB[1], sB + (256 + tid) * 16);
    kstep();
    gl_lds16<192>(pA[0], sA + tid * 16);
    gl_lds16<192>(pA[1], sA + (256 + tid) * 16);
    gl_lds16<192>(pB[0], sB + tid * 16);
    gl_lds16<192>(pB[1], sB + (256 + tid) * 16);
    kstep();

    float* G = (float*)smem_raw;  // [32 rows][pad 132] fp32 per pass
#pragma unroll
    for (int p = 0; p < 4; ++p) {
      if (wm == (p >> 1)) {
#pragma unroll
        for (int ii = 0; ii < 2; ++ii) {
          const int i = (p & 1) * 2 + ii;
#pragma unroll
          for (int j = 0; j < 4; ++j)
#pragma unroll
            for (int r = 0; r < 4; ++r)
              G[(ii * 16 + q * 4 + r) * 132 + wn * 64 + j * 16 + c16] =
                  acc[i][j][r];
        }
      }
      __syncthreads();
      {
        const int rr = tid >> 3;    // 0..31
        const int chunk = tid & 7;  // 16-float chunks
        const long krow = rowBase + p * 32 + rr;
        float v = 0.0f;
#pragma unroll
        for (int u = 0; u < 4; ++u) {
          const float4 g = *(const float4*)(G + rr * 132 + chunk * 16 + u * 4);
          const float4 w4 = *(const float4*)(W + krow * L_DIM + colBase +
                                             chunk * 16 + u * 4);
          v += g.x * w4.x + g.y * w4.y + g.z * w4.z + g.w * w4.w;
        }
        v += __shfl_xor(v, 1, 64);
        v += __shfl_xor(v, 2, 64);
        v += __shfl_xor(v, 4, 64);
        if (chunk == 0) atomicAdd(&simpos[n * L_DIM + krow], v);
      }
      __syncthreads();
    }
  }
}

// ---------------------------------------------------------------------------
// Kernel 3: 128-block finalize; sums the 8 rowsum replicas per row.
// loss = mean over rows of log(rowsum_neg + exp(simpos)) - simpos
// ---------------------------------------------------------------------------
__global__ __launch_bounds__(256) void k_finalize(const float* __restrict__ rowsum8,
                                                  const float* __restrict__ simpos,
                                                  float* __restrict__ out) {
  const int gid = blockIdx.x * 256 + threadIdx.x;  // one row per thread
  float rs = 0.0f;
#pragma unroll
  for (int x = 0; x < 8; ++x) rs += rowsum8[x * NROWS + gid];
  const float sp = simpos[gid];
  float v = __logf(rs + __expf(sp)) - sp;
#pragma unroll
  for (int off = 1; off < 64; off <<= 1) v += __shfl_xor(v, off, 64);
  __shared__ float ws[4];
  if ((threadIdx.x & 63) == 0) ws[threadIdx.x >> 6] = v;
  __syncthreads();
  if (threadIdx.x == 0)
    atomicAdd(out, (ws[0] + ws[1] + ws[2] + ws[3]) * (1.0f / (float)NROWS));
}

// ---------------------------------------------------------------------------
// Workspace layout (bytes):
//   [0,       8388608)  E fp4 [32768, 256 B]   (x32 scaled e2m1)
//   [8388608, 9437184)  rowsum8 fp32 [8][32768]  (per-XCD replicas, 1 MB)
//   [9437184, 9568256)  simpos fp32 [32768]
// ---------------------------------------------------------------------------
extern "C" void kernel_launch(void* const* d_in, const int* in_sizes, int n_in,
                              void* d_out, int out_size, void* d_ws, size_t ws_size,
                              hipStream_t stream) {
  const float* emb = (const float*)d_in[0];
  const float* weight = (const float*)d_in[1];
  const int* negidx = (const int*)d_in[2];
  float* out = (float*)d_out;
  char* ws = (char*)d_ws;

  uint8_t* E4 = (uint8_t*)ws;
  float* rowsum8 = (float*)(ws + 8388608);
  float* simpos = (float*)(ws + 9437184);

  k_normalize<<<NROWS / 4, 256, 0, stream>>>(emb, E4, rowsum8, out);
  k_gemm_fused<<<3072, 256, 0, stream>>>(E4, negidx, weight, rowsum8, simpos);
  k_finalize<<<NROWS / 256, 256, 0, stream>>>(rowsum8, simpos, out);
}

// Round 17
// 176.811 us; speedup vs baseline: 1.0780x; 1.0780x over previous
//
#include <hip/hip_runtime.h>
#include <hip/hip_bf16.h>
#include <stdint.h>

// Problem constants
#define L_DIM 1024
#define C_DIM 512       // channels (elements)
#define CB4 256         // fp4 row stride in BYTES (512 elems * 4 bit)
#define N_BATCH 32
#define M_NEG 4096
#define NROWS (N_BATCH * L_DIM) // 32768

typedef float f32x4 __attribute__((ext_vector_type(4)));
typedef int i32x4 __attribute__((ext_vector_type(4)));
typedef int i32x8 __attribute__((ext_vector_type(8)));

// E stored as fp4 e2m1 scaled by 32 (clip at |x|=0.1875 ~ 4.3 sigma);
// e8m0 scale 122 (=2^-5) on both MFMA operands gives exact 1/1024 comp.
#define E4_SCALE 32.0f
#define MX_SCALE 122
#define FMT_FP4 4

// DMA immediate offset must be a compile-time constant -> template param.
template <int GOFF>
__device__ __forceinline__ void gl_lds16(const uint8_t* g, uint8_t* l) {
  __builtin_amdgcn_global_load_lds(
      (const __attribute__((address_space(1))) void*)g,
      (__attribute__((address_space(3))) void*)l, 16, GOFF, 0);
}

// fp4 e2m1 round-to-nearest encode of pre-scaled value.
__device__ __forceinline__ uint32_t fp4_enc(float x) {
  const uint32_t s = (__float_as_uint(x) >> 31) << 3;
  const float a = fabsf(x);
  uint32_t c;
  c = a < 0.25f ? 0u
    : a < 0.75f ? 1u
    : a < 1.25f ? 2u
    : a < 1.75f ? 3u
    : a < 2.5f  ? 4u
    : a < 3.5f  ? 5u
    : a < 5.0f  ? 6u : 7u;
  return s | c;
}

// fp4 operand tuple: HW reads only v[0:3] for FMT_FP4; upper half undef.
__device__ __forceinline__ i32x8 fp4_op(i32x4 d) {
  return __builtin_shufflevector(d, d, 0, 1, 2, 3, -1, -1, -1, -1);
}

// LDS swizzle phase (verified 0-conflict in R14): bank window = 128 B =
// two 64 B rows -> phase advances per 2 rows.
__device__ __forceinline__ int swz(int row) { return (row >> 1) & 3; }

// ---------------------------------------------------------------------------
// Kernel 1: row-wise L2 normalize fp32 [32768, 512] -> fp4 e2m1 (x32 scaled).
// Blocks 0..127 zero the 128 KB simpos (atomic target); block 0 zeroes the
// loss scalar. rowsum4 is plain-stored by every owner -> no zeroing needed.
// ---------------------------------------------------------------------------
__global__ __launch_bounds__(256) void k_normalize(const float* __restrict__ emb,
                                                   uint8_t* __restrict__ out,
                                                   float* __restrict__ simpos,
                                                   float* __restrict__ loss_out) {
  if (blockIdx.x < 128) simpos[blockIdx.x * 256 + threadIdx.x] = 0.0f;
  if (blockIdx.x == 0 && threadIdx.x == 0) loss_out[0] = 0.0f;
  const int lane = threadIdx.x & 63;
  const int wave = threadIdx.x >> 6;
  const long row = (long)blockIdx.x * 4 + wave;
  const float4* src = (const float4*)(emb + row * C_DIM);
  float4 v0 = src[2 * lane];
  float4 v1 = src[2 * lane + 1];
  float ss = v0.x * v0.x + v0.y * v0.y + v0.z * v0.z + v0.w * v0.w +
             v1.x * v1.x + v1.y * v1.y + v1.z * v1.z + v1.w * v1.w;
#pragma unroll
  for (int off = 1; off < 64; off <<= 1) ss += __shfl_xor(ss, off, 64);
  const float s = E4_SCALE / fmaxf(sqrtf(ss), 1e-12f);
  uint32_t pk = fp4_enc(v0.x * s)        | (fp4_enc(v0.y * s) << 4) |
                (fp4_enc(v0.z * s) << 8) | (fp4_enc(v0.w * s) << 12) |
                (fp4_enc(v1.x * s) << 16)| (fp4_enc(v1.y * s) << 20) |
                (fp4_enc(v1.z * s) << 24)| (fp4_enc(v1.w * s) << 28);
  ((uint32_t*)(out + row * CB4))[lane] = pk;
}

// ---------------------------------------------------------------------------
// Kernel 2 (FUSED), 3072 blocks:
// MODE 0 (bid < 1024): E-STATIONARY PERSISTENT TILES, ZERO ATOMICS.
//   Block owns 128 E rows (contiguous -> staged full-K once into 4 slabs,
//   32 KB) and streams 8 idx-gathered neg tiles through an 8 KB slab.
//   Each (negQuarter, E-row) has exactly ONE writer -> rowsum partials are
//   PLAIN STORES to rowsum4[negQ][row]; finalize sums the 4 partitions.
//   (R15/R16 lesson: device-scope fp32 atomics are memory-side on gfx950 --
//   write bytes scale with atomic COUNT (R14 262K->5MB, R15/16 2M->61MB);
//   locality/replicas don't help. So: eliminate them by ownership.)
//   Per-row exp-sums ride in 16 registers across tiles; one c16-shuffle
//   reduce + LDS wn-combine per block at the end.
//   XCD map: xcd=bid&7, s=bid>>3: negQ=s&3, eTile=xcd*32+(s>>2)
//     -> per XCD: E band 1 MB + neg quarter 256 KB, L2-resident.
// MODE 1 (bid >= 1024): R14 structure verbatim (Gram x W epilogue).
// LDS 40960 B; target <=64 VGPR + 64 AGPR -> 4 blocks/CU.
// ---------------------------------------------------------------------------
__global__ __launch_bounds__(256, 4) void k_gemm_fused(
    const uint8_t* __restrict__ E4, const int* __restrict__ idx,
    const float* __restrict__ W, float* __restrict__ rowsum4,
    float* __restrict__ simpos) {
  __shared__ __align__(16) unsigned char smem_raw[40960];

  const int tid = threadIdx.x;
  const int lane = tid & 63;
  const int wave = tid >> 6;
  const int wm = wave >> 1, wn = wave & 1;
  const int q = lane >> 4, c16 = lane & 15;

  const int bid = blockIdx.x;

  if (bid < 1024) {
    // ================= MODE 0: E-stationary =================
    uint8_t* sE = (uint8_t*)smem_raw;        // 4 slabs [128][64B] = 32 KB
    uint8_t* sN = sE + 32768;                // [128][64B] = 8 KB
    const int xcd = bid & 7, s = bid >> 3;   // s 0..127
    const int negQ = s & 3;
    const long eBase = ((long)xcd * 32 + (s >> 2)) * 128;
    const int negBase = negQ * 1024;

    // Stage the 128 E rows, full K (8 DMAs/thread, once).
    {
      const uint8_t* pE[2];
#pragma unroll
      for (int r = 0; r < 2; ++r) {
        const int c = r * 256 + tid;          // chunk 0..511 per slab
        const int rw = c >> 2, cb = c & 3;
        pE[r] = E4 + (eBase + rw) * CB4 + (cb ^ swz(rw)) * 16;
      }
      gl_lds16<0>(pE[0], sE + tid * 16);
      gl_lds16<0>(pE[1], sE + (256 + tid) * 16);
      gl_lds16<64>(pE[0], sE + 8192 + tid * 16);
      gl_lds16<64>(pE[1], sE + 8192 + (256 + tid) * 16);
      gl_lds16<128>(pE[0], sE + 16384 + tid * 16);
      gl_lds16<128>(pE[1], sE + 16384 + (256 + tid) * 16);
      gl_lds16<192>(pE[0], sE + 24576 + tid * 16);
      gl_lds16<192>(pE[1], sE + 24576 + (256 + tid) * 16);
    }

    // Neg staging thread-constants.
    const int rw0 = tid >> 2, cb0 = tid & 3;
    const int c1 = 256 + tid;
    const int rw1 = c1 >> 2, cb1 = c1 & 3;
    const int off0 = (cb0 ^ swz(rw0)) * 16;
    const int off1 = (cb1 ^ swz(rw1)) * 16;
    const int* ip0 = idx + negBase + rw0;
    const int* ip1 = idx + negBase + rw1;

    // Hoisted LDS fragment byte-offsets. A = E (rows), B = neg (cols).
    int ldsA[4], ldsB[4];
#pragma unroll
    for (int j = 0; j < 4; ++j) {
      const int rowA = wm * 64 + j * 16 + c16;
      ldsA[j] = rowA * 64 + (q ^ swz(rowA)) * 16;
      const int rowB = wn * 64 + j * 16 + c16;
      ldsB[j] = rowB * 64 + (q ^ swz(rowB)) * 16;
    }

    float s16[16];
#pragma unroll
    for (int v = 0; v < 16; ++v) s16[v] = 0.0f;

    for (int t = 0; t < 8; ++t) {
      const uint8_t* q0 = E4 + (long)ip0[t * 128] * CB4 + off0;
      const uint8_t* q1 = E4 + (long)ip1[t * 128] * CB4 + off1;
      f32x4 acc[4][4] = {};
      auto kstep = [&](int ks) {
        __syncthreads();
        i32x8 bfr[4];
#pragma unroll
        for (int j = 0; j < 4; ++j)
          bfr[j] = fp4_op(*(const i32x4*)(sN + ldsB[j]));
#pragma unroll
        for (int i = 0; i < 4; ++i) {
          i32x8 af = fp4_op(*(const i32x4*)(sE + ks * 8192 + ldsA[i]));
#pragma unroll
          for (int j = 0; j < 4; ++j)
            acc[i][j] = __builtin_amdgcn_mfma_scale_f32_16x16x128_f8f6f4(
                af, bfr[j], acc[i][j], FMT_FP4, FMT_FP4,
                0, MX_SCALE, 0, MX_SCALE);
        }
        __syncthreads();
      };
      gl_lds16<0>(q0, sN + tid * 16);
      gl_lds16<0>(q1, sN + (256 + tid) * 16);
      kstep(0);
      gl_lds16<64>(q0, sN + tid * 16);
      gl_lds16<64>(q1, sN + (256 + tid) * 16);
      kstep(1);
      gl_lds16<128>(q0, sN + tid * 16);
      gl_lds16<128>(q1, sN + (256 + tid) * 16);
      kstep(2);
      gl_lds16<192>(q0, sN + tid * 16);
      gl_lds16<192>(q1, sN + (256 + tid) * 16);
      kstep(3);

      // Fold this tile's 128 neg cols into the running per-row sums.
#pragma unroll
      for (int i = 0; i < 4; ++i)
#pragma unroll
        for (int r = 0; r < 4; ++r)
          s16[i * 4 + r] += __expf(acc[i][0][r]) + __expf(acc[i][1][r]) +
                            __expf(acc[i][2][r]) + __expf(acc[i][3][r]);
    }

    // Cross-c16 reduce (cols within this wn half), then wn-combine via LDS,
    // then ONE plain store per row (sole writer of (negQ, row)).
#pragma unroll
    for (int v = 0; v < 16; ++v) {
      s16[v] += __shfl_xor(s16[v], 1, 64);
      s16[v] += __shfl_xor(s16[v], 2, 64);
      s16[v] += __shfl_xor(s16[v], 4, 64);
      s16[v] += __shfl_xor(s16[v], 8, 64);
    }
    float* red = (float*)sN;  // 128 floats; sN free after last kstep barrier
    if (wn == 1 && c16 == 0) {
#pragma unroll
      for (int i = 0; i < 4; ++i)
#pragma unroll
        for (int r = 0; r < 4; ++r)
          red[wm * 64 + i * 16 + q * 4 + r] = s16[i * 4 + r];
    }
    __syncthreads();
    if (wn == 0 && c16 == 0) {
      float* dst = rowsum4 + (long)negQ * NROWS + eBase;
#pragma unroll
      for (int i = 0; i < 4; ++i)
#pragma unroll
        for (int r = 0; r < 4; ++r) {
          const int row = wm * 64 + i * 16 + q * 4 + r;
          dst[row] = s16[i * 4 + r] + red[row];
        }
    }
  } else {
    // ================= MODE 1: Gram x W (R14 verbatim) =================
    uint8_t* sA = (uint8_t*)smem_raw;        // [128][64B] = 8 KB
    uint8_t* sB = sA + 8192;                 // [128][64B] = 8 KB
    const int t = bid - 1024;
    const int xcd = t & 7, slot = t >> 3;
    const long n = xcd * 4 + (slot & 3);
    const int inner = slot >> 2;             // 0..63
    const long rowBase = (long)(inner & 7) * 128;
    const long colBase = (long)(inner >> 3) * 128;
    const long aBase = n * L_DIM + rowBase;

    const uint8_t* pA[2];
    const uint8_t* pB[2];
#pragma unroll
    for (int r = 0; r < 2; ++r) {
      const int c = r * 256 + tid;
      const int rw = c >> 2, cb = c & 3;
      pA[r] = E4 + (aBase + rw) * CB4 + (cb ^ swz(rw)) * 16;
      pB[r] = E4 + (n * L_DIM + colBase + rw) * CB4 + (cb ^ swz(rw)) * 16;
    }
    int ldsB[4], ldsA[4];
#pragma unroll
    for (int j = 0; j < 4; ++j) {
      const int rowB = wn * 64 + j * 16 + c16;
      ldsB[j] = rowB * 64 + (q ^ swz(rowB)) * 16;
      const int rowA = wm * 64 + j * 16 + c16;
      ldsA[j] = rowA * 64 + (q ^ swz(rowA)) * 16;
    }

    f32x4 acc[4][4] = {};
    auto kstep = [&]() {
      __syncthreads();
      i32x8 bfr[4];
#pragma unroll
      for (int j = 0; j < 4; ++j)
        bfr[j] = fp4_op(*(const i32x4*)(sB + ldsB[j]));
#pragma unroll
      for (int i = 0; i < 4; ++i) {
        i32x8 af = fp4_op(*(const i32x4*)(sA + ldsA[i]));
#pragma unroll
        for (int j = 0; j < 4; ++j)
          acc[i][j] = __builtin_amdgcn_mfma_scale_f32_16x16x128_f8f6f4(
              af, bfr[j], acc[i][j], FMT_FP4, FMT_FP4,
              0, MX_SCALE, 0, MX_SCALE);
      }
      __syncthreads();
    };
    gl_lds16<0>(pA[0], sA + tid * 16);
    gl_lds16<0>(pA[1], sA + (256 + tid) * 16);
    gl_lds16<0>(pB[0], sB + tid * 16);
    gl_lds16<0>(pB[1], sB + (256 + tid) * 16);
    kstep();
    gl_lds16<64>(pA[0], sA + tid * 16);
    gl_lds16<64>(pA[1], sA + (256 + tid) * 16);
    gl_lds16<64>(pB[0], sB + tid * 16);
    gl_lds16<64>(pB[1], sB + (256 + tid) * 16);
    kstep();
    gl_lds16<128>(pA[0], sA + tid * 16);
    gl_lds16<128>(pA[1], sA + (256 + tid) * 16);
    gl_lds16<128>(pB[0], sB + tid * 16);
    gl_lds16<128>(pB[1], sB + (256 + tid) * 16);
    kstep();
    gl_lds16<192>(pA[0], sA + tid * 16);
    gl_lds16<192>(pA[1], sA + (256 + tid) * 16);
    gl_lds16<192>(pB[0], sB + tid * 16);
    gl_lds16<192>(pB[1], sB + (256 + tid) * 16);
    kstep();

    float* G = (float*)smem_raw;  // [32 rows][pad 132] fp32 per pass
#pragma unroll
    for (int p = 0; p < 4; ++p) {
      if (wm == (p >> 1)) {
#pragma unroll
        for (int ii = 0; ii < 2; ++ii) {
          const int i = (p & 1) * 2 + ii;
#pragma unroll
          for (int j = 0; j < 4; ++j)
#pragma unroll
            for (int r = 0; r < 4; ++r)
              G[(ii * 16 + q * 4 + r) * 132 + wn * 64 + j * 16 + c16] =
                  acc[i][j][r];
        }
      }
      __syncthreads();
      {
        const int rr = tid >> 3;    // 0..31
        const int chunk = tid & 7;  // 16-float chunks
        const long krow = rowBase + p * 32 + rr;
        float v = 0.0f;
#pragma unroll
        for (int u = 0; u < 4; ++u) {
          const float4 g = *(const float4*)(G + rr * 132 + chunk * 16 + u * 4);
          const float4 w4 = *(const float4*)(W + krow * L_DIM + colBase +
                                             chunk * 16 + u * 4);
          v += g.x * w4.x + g.y * w4.y + g.z * w4.z + g.w * w4.w;
        }
        v += __shfl_xor(v, 1, 64);
        v += __shfl_xor(v, 2, 64);
        v += __shfl_xor(v, 4, 64);
        if (chunk == 0) atomicAdd(&simpos[n * L_DIM + krow], v);
      }
      __syncthreads();
    }
  }
}

// ---------------------------------------------------------------------------
// Kernel 3: 128-block finalize; sums the 4 rowsum partitions per row.
// loss = mean over rows of log(rowsum_neg + exp(simpos)) - simpos
// ---------------------------------------------------------------------------
__global__ __launch_bounds__(256) void k_finalize(const float* __restrict__ rowsum4,
                                                  const float* __restrict__ simpos,
                                                  float* __restrict__ out) {
  const int gid = blockIdx.x * 256 + threadIdx.x;  // one row per thread
  const float rs = rowsum4[gid] + rowsum4[NROWS + gid] +
                   rowsum4[2 * NROWS + gid] + rowsum4[3 * NROWS + gid];
  const float sp = simpos[gid];
  float v = __logf(rs + __expf(sp)) - sp;
#pragma unroll
  for (int off = 1; off < 64; off <<= 1) v += __shfl_xor(v, off, 64);
  __shared__ float ws[4];
  if ((threadIdx.x & 63) == 0) ws[threadIdx.x >> 6] = v;
  __syncthreads();
  if (threadIdx.x == 0)
    atomicAdd(out, (ws[0] + ws[1] + ws[2] + ws[3]) * (1.0f / (float)NROWS));
}

// ---------------------------------------------------------------------------
// Workspace layout (bytes):
//   [0,       8388608)  E fp4 [32768, 256 B]   (x32 scaled e2m1)
//   [8388608, 8912896)  rowsum4 fp32 [4][32768]  (neg-quarter partials)
//   [8912896, 9043968)  simpos fp32 [32768]
// ---------------------------------------------------------------------------
extern "C" void kernel_launch(void* const* d_in, const int* in_sizes, int n_in,
                              void* d_out, int out_size, void* d_ws, size_t ws_size,
                              hipStream_t stream) {
  const float* emb = (const float*)d_in[0];
  const float* weight = (const float*)d_in[1];
  const int* negidx = (const int*)d_in[2];
  float* out = (float*)d_out;
  char* ws = (char*)d_ws;

  uint8_t* E4 = (uint8_t*)ws;
  float* rowsum4 = (float*)(ws + 8388608);
  float* simpos = (float*)(ws + 8912896);

  k_normalize<<<NROWS / 4, 256, 0, stream>>>(emb, E4, simpos, out);
  k_gemm_fused<<<3072, 256, 0, stream>>>(E4, negidx, weight, rowsum4, simpos);
  k_finalize<<<NROWS / 256, 256, 0, stream>>>(rowsum4, simpos, out);
}

// Round 18
// 168.331 us; speedup vs baseline: 1.1323x; 1.0504x over previous
//
#include <hip/hip_runtime.h>
#include <hip/hip_bf16.h>
#include <stdint.h>

// Problem constants
#define L_DIM 1024
#define C_DIM 512       // channels (elements)
#define CB4 256         // fp4 row stride in BYTES (512 elems * 4 bit)
#define N_BATCH 32
#define M_NEG 4096
#define NROWS (N_BATCH * L_DIM) // 32768

typedef float f32x4 __attribute__((ext_vector_type(4)));
typedef int i32x4 __attribute__((ext_vector_type(4)));
typedef int i32x8 __attribute__((ext_vector_type(8)));

// E stored as fp4 e2m1 scaled by 32 (clip at |x|=0.1875 ~ 4.3 sigma);
// e8m0 scale 122 (=2^-5) on both MFMA operands gives exact 1/1024 comp.
#define E4_SCALE 32.0f
#define MX_SCALE 122
#define FMT_FP4 4

// DMA immediate offset must be a compile-time constant -> template param.
template <int GOFF>
__device__ __forceinline__ void gl_lds16(const uint8_t* g, uint8_t* l) {
  __builtin_amdgcn_global_load_lds(
      (const __attribute__((address_space(1))) void*)g,
      (__attribute__((address_space(3))) void*)l, 16, GOFF, 0);
}

// fp4 e2m1 round-to-nearest encode of pre-scaled value.
__device__ __forceinline__ uint32_t fp4_enc(float x) {
  const uint32_t s = (__float_as_uint(x) >> 31) << 3;
  const float a = fabsf(x);
  uint32_t c;
  c = a < 0.25f ? 0u
    : a < 0.75f ? 1u
    : a < 1.25f ? 2u
    : a < 1.75f ? 3u
    : a < 2.5f  ? 4u
    : a < 3.5f  ? 5u
    : a < 5.0f  ? 6u : 7u;
  return s | c;
}

// fp4 operand tuple: HW reads only v[0:3] for FMT_FP4; upper half undef.
__device__ __forceinline__ i32x8 fp4_op(i32x4 d) {
  return __builtin_shufflevector(d, d, 0, 1, 2, 3, -1, -1, -1, -1);
}

// LDS swizzle phase (verified 0-conflict in R14): bank window = 128 B =
// two 64 B rows -> phase advances per 2 rows.
__device__ __forceinline__ int swz(int row) { return (row >> 1) & 3; }

// ---------------------------------------------------------------------------
// Kernel 1: row-wise L2 normalize fp32 [32768, 512] -> fp4 e2m1 (x32 scaled).
// Blocks 0..255 also zero the rowsum+simpos accumulators; block 0 zeroes
// the loss scalar.
// ---------------------------------------------------------------------------
__global__ __launch_bounds__(256) void k_normalize(const float* __restrict__ emb,
                                                   uint8_t* __restrict__ out,
                                                   float* __restrict__ zerobuf,
                                                   float* __restrict__ loss_out) {
  if (blockIdx.x < 256) zerobuf[blockIdx.x * 256 + threadIdx.x] = 0.0f;
  if (blockIdx.x == 0 && threadIdx.x == 0) loss_out[0] = 0.0f;
  const int lane = threadIdx.x & 63;
  const int wave = threadIdx.x >> 6;
  const long row = (long)blockIdx.x * 4 + wave;
  const float4* src = (const float4*)(emb + row * C_DIM);
  float4 v0 = src[2 * lane];
  float4 v1 = src[2 * lane + 1];
  float ss = v0.x * v0.x + v0.y * v0.y + v0.z * v0.z + v0.w * v0.w +
             v1.x * v1.x + v1.y * v1.y + v1.z * v1.z + v1.w * v1.w;
#pragma unroll
  for (int off = 1; off < 64; off <<= 1) ss += __shfl_xor(ss, off, 64);
  const float s = E4_SCALE / fmaxf(sqrtf(ss), 1e-12f);
  uint32_t pk = fp4_enc(v0.x * s)        | (fp4_enc(v0.y * s) << 4) |
                (fp4_enc(v0.z * s) << 8) | (fp4_enc(v0.w * s) << 12) |
                (fp4_enc(v1.x * s) << 16)| (fp4_enc(v1.y * s) << 20) |
                (fp4_enc(v1.z * s) << 24)| (fp4_enc(v1.w * s) << 28);
  ((uint32_t*)(out + row * CB4))[lane] = pk;
}

// ---------------------------------------------------------------------------
// Kernel 2 (FUSED), 10240 blocks — R14 configuration, the session argmin.
// (R15-R17 persistent-tile variants all regressed: scattered gather on the
// kstep critical path + unexplained 60+ MB HBM writes. This structure's
// remaining MfmaUtil ~25% is the documented m97-plateau: per-kstep
// vmcnt(0)+barrier drain, unfixable at HIP level; the 64+64 register
// quantum pins the tile size that would amortize it.)
// 128x128 tile, MX-fp4 (mfma_scale 16x16x128), 4 ksteps, 20.5 KB LDS,
// 64 VGPR + 64 AGPR -> 4 blocks/CU (38% occupancy), 0 bank conflicts.
// XCD swizzle (dispatch round-robin xcd ~= bid&7):
//   mode 1 (bid<2048):  xcd=bid&7; slot=bid>>3; n=xcd*4+(slot&3);
//       inner=slot>>2; rowTile=inner&7, colTile=inner>>3.  (~1 MB/XCD)
//   mode 0 (bid>=2048): t=bid-2048; xcd=t&7; slot=t>>3;
//       rowTile=xcd*32+(slot&31), colTile=slot>>5.  (A 1MB + B 1MB /XCD)
// ---------------------------------------------------------------------------
__global__ __launch_bounds__(256, 4) void k_gemm_fused(
    const uint8_t* __restrict__ E4, const int* __restrict__ idx,
    const float* __restrict__ W, float* __restrict__ rowsum,
    float* __restrict__ simpos) {
  __shared__ __align__(16) unsigned char smem_raw[20480];
  uint8_t* sA = (uint8_t*)smem_raw;          // [128][64B] = 8 KB
  uint8_t* sB = sA + 128 * 64;               // [128][64B] = 8 KB

  const int tid = threadIdx.x;
  const int lane = tid & 63;
  const int wave = tid >> 6;
  const int wm = wave >> 1, wn = wave & 1;
  const int q = lane >> 4, c16 = lane & 15;

  const int bid = blockIdx.x;
  const bool is0 = bid >= 2048;
  long rowBase, colBase, n = 0;
  if (is0) {
    const int t = bid - 2048;
    const int xcd = t & 7, slot = t >> 3;
    rowBase = (long)(xcd * 32 + (slot & 31)) * 128;
    colBase = (long)(slot >> 5) * 128;
  } else {
    const int xcd = bid & 7, slot = bid >> 3;
    n = xcd * 4 + (slot & 3);
    const int inner = slot >> 2;          // 0..63
    rowBase = (long)(inner & 7) * 128;
    colBase = (long)(inner >> 3) * 128;
  }
  const long aBase = is0 ? rowBase : n * L_DIM + rowBase;

  // Staging base pointers (2 A + 2 B); per-kstep advance is the ks*64
  // IMMEDIATE offset on the DMA (template) -> zero K-loop address VALU.
  const uint8_t* pA[2];
  const uint8_t* pB[2];
#pragma unroll
  for (int r = 0; r < 2; ++r) {
    const int c = r * 256 + tid;          // 16B chunk 0..511
    const int rw = c >> 2, cb = c & 3;    // row 0..127, group 0..3
    pA[r] = E4 + (aBase + rw) * CB4 + (cb ^ swz(rw)) * 16;
    const long bRow = is0 ? (long)idx[colBase + rw] : n * L_DIM + colBase + rw;
    pB[r] = E4 + bRow * CB4 + (cb ^ swz(rw)) * 16;
  }

  // Hoisted LDS fragment byte-offsets (loop-invariant).
  int ldsB[4], ldsA[4];
#pragma unroll
  for (int j = 0; j < 4; ++j) {
    const int rowB = wn * 64 + j * 16 + c16;
    ldsB[j] = rowB * 64 + (q ^ swz(rowB)) * 16;
    const int rowA = wm * 64 + j * 16 + c16;
    ldsA[j] = rowA * 64 + (q ^ swz(rowA)) * 16;
  }

  f32x4 acc[4][4] = {};

  auto kstep = [&]() {
    __syncthreads();
    i32x8 bfr[4];
#pragma unroll
    for (int j = 0; j < 4; ++j)
      bfr[j] = fp4_op(*(const i32x4*)(sB + ldsB[j]));
#pragma unroll
    for (int i = 0; i < 4; ++i) {
      i32x8 af = fp4_op(*(const i32x4*)(sA + ldsA[i]));
#pragma unroll
      for (int j = 0; j < 4; ++j)
        acc[i][j] = __builtin_amdgcn_mfma_scale_f32_16x16x128_f8f6f4(
            af, bfr[j], acc[i][j], FMT_FP4, FMT_FP4,
            0, MX_SCALE, 0, MX_SCALE);
    }
    __syncthreads();
  };

  // K-step 0
  gl_lds16<0>(pA[0], sA + tid * 16);
  gl_lds16<0>(pA[1], sA + (256 + tid) * 16);
  gl_lds16<0>(pB[0], sB + tid * 16);
  gl_lds16<0>(pB[1], sB + (256 + tid) * 16);
  kstep();
  // K-step 1
  gl_lds16<64>(pA[0], sA + tid * 16);
  gl_lds16<64>(pA[1], sA + (256 + tid) * 16);
  gl_lds16<64>(pB[0], sB + tid * 16);
  gl_lds16<64>(pB[1], sB + (256 + tid) * 16);
  kstep();
  // K-step 2
  gl_lds16<128>(pA[0], sA + tid * 16);
  gl_lds16<128>(pA[1], sA + (256 + tid) * 16);
  gl_lds16<128>(pB[0], sB + tid * 16);
  gl_lds16<128>(pB[1], sB + (256 + tid) * 16);
  kstep();
  // K-step 3
  gl_lds16<192>(pA[0], sA + tid * 16);
  gl_lds16<192>(pA[1], sA + (256 + tid) * 16);
  gl_lds16<192>(pB[0], sB + tid * 16);
  gl_lds16<192>(pB[1], sB + (256 + tid) * 16);
  kstep();

  // Epilogue. C/D layout: col = c16, row = q*4 + reg (per 16x16 tile).
  if (is0) {
    float* S = (float*)smem_raw;  // [4 waves][64 rows][pad 20] = 20480 B
#pragma unroll
    for (int i = 0; i < 4; ++i)
#pragma unroll
      for (int r = 0; r < 4; ++r) {
        const float s = __expf(acc[i][0][r]) + __expf(acc[i][1][r]) +
                        __expf(acc[i][2][r]) + __expf(acc[i][3][r]);
        S[wave * 1280 + (i * 16 + q * 4 + r) * 20 + c16] = s;
      }
    __syncthreads();
    if (tid < 128) {
      const int wm2 = tid >> 6, row64 = tid & 63;  // global row = rowBase+tid
      const float* p0 = (const float*)S + (wm2 * 2 + 0) * 1280 + row64 * 20;
      const float* p1 = (const float*)S + (wm2 * 2 + 1) * 1280 + row64 * 20;
      float4 t0 = ((const float4*)p0)[0], t1 = ((const float4*)p0)[1];
      float4 t2 = ((const float4*)p0)[2], t3 = ((const float4*)p0)[3];
      float4 u0 = ((const float4*)p1)[0], u1 = ((const float4*)p1)[1];
      float4 u2 = ((const float4*)p1)[2], u3 = ((const float4*)p1)[3];
      float v = t0.x + t0.y + t0.z + t0.w + t1.x + t1.y + t1.z + t1.w +
                t2.x + t2.y + t2.z + t2.w + t3.x + t3.y + t3.z + t3.w +
                u0.x + u0.y + u0.z + u0.w + u1.x + u1.y + u1.z + u1.w +
                u2.x + u2.y + u2.z + u2.w + u3.x + u3.y + u3.z + u3.w;
      atomicAdd(&rowsum[rowBase + tid], v);
    }
  } else {
    float* G = (float*)smem_raw;  // [32 rows][pad 132] fp32 per pass
#pragma unroll
    for (int p = 0; p < 4; ++p) {  // 32-row passes
      if (wm == (p >> 1)) {
#pragma unroll
        for (int ii = 0; ii < 2; ++ii) {
          const int i = (p & 1) * 2 + ii;
#pragma unroll
          for (int j = 0; j < 4; ++j)
#pragma unroll
            for (int r = 0; r < 4; ++r)
              G[(ii * 16 + q * 4 + r) * 132 + wn * 64 + j * 16 + c16] =
                  acc[i][j][r];
        }
      }
      __syncthreads();
      {
        const int rr = tid >> 3;    // 0..31
        const int chunk = tid & 7;  // 16-float chunks
        const long krow = rowBase + p * 32 + rr;
        float v = 0.0f;
#pragma unroll
        for (int u = 0; u < 4; ++u) {
          const float4 g =
              *(const float4*)(G + rr * 132 + chunk * 16 + u * 4);
          const float4 w4 = *(const float4*)(W + krow * L_DIM + colBase +
                                             chunk * 16 + u * 4);
          v += g.x * w4.x + g.y * w4.y + g.z * w4.z + g.w * w4.w;
        }
        v += __shfl_xor(v, 1, 64);
        v += __shfl_xor(v, 2, 64);
        v += __shfl_xor(v, 4, 64);
        if (chunk == 0) atomicAdd(&simpos[n * L_DIM + krow], v);
      }
      __syncthreads();
    }
  }
}

// ---------------------------------------------------------------------------
// Kernel 3: 128-block finalize; out[0] pre-zeroed by k_normalize.
// loss = mean over rows of log(rowsum_neg + exp(simpos)) - simpos
// ---------------------------------------------------------------------------
__global__ __launch_bounds__(256) void k_finalize(const float* __restrict__ rowsum,
                                                  const float* __restrict__ simpos,
                                                  float* __restrict__ out) {
  const int gid = blockIdx.x * 256 + threadIdx.x;  // one row per thread
  const float sp = simpos[gid];
  float v = __logf(rowsum[gid] + __expf(sp)) - sp;
#pragma unroll
  for (int off = 1; off < 64; off <<= 1) v += __shfl_xor(v, off, 64);
  __shared__ float ws[4];
  if ((threadIdx.x & 63) == 0) ws[threadIdx.x >> 6] = v;
  __syncthreads();
  if (threadIdx.x == 0)
    atomicAdd(out, (ws[0] + ws[1] + ws[2] + ws[3]) * (1.0f / (float)NROWS));
}

// ---------------------------------------------------------------------------
// Workspace layout (bytes):
//   [0,       8388608)  E fp4 [32768, 256 B]   (x32 scaled e2m1)
//   [8388608, 8519680)  rowsum fp32 [32768]
//   [8519680, 8650752)  simpos fp32 [32768]    (contiguous with rowsum)
// ---------------------------------------------------------------------------
extern "C" void kernel_launch(void* const* d_in, const int* in_sizes, int n_in,
                              void* d_out, int out_size, void* d_ws, size_t ws_size,
                              hipStream_t stream) {
  const float* emb = (const float*)d_in[0];
  const float* weight = (const float*)d_in[1];
  const int* negidx = (const int*)d_in[2];
  float* out = (float*)d_out;
  char* ws = (char*)d_ws;

  uint8_t* E4 = (uint8_t*)ws;
  float* rowsum = (float*)(ws + 8388608);
  float* simpos = (float*)(ws + 8519680);

  k_normalize<<<NROWS / 4, 256, 0, stream>>>(emb, E4, rowsum, out);
  k_gemm_fused<<<10240, 256, 0, stream>>>(E4, negidx, weight, rowsum, simpos);
  k_finalize<<<NROWS / 256, 256, 0, stream>>>(rowsum, simpos, out);
}